// Round 4
// baseline (87.427 us; speedup 1.0000x reference)
//
#include <hip/hip_runtime.h>

// Problem geometry (fixed by setup_inputs):
//   img: (1080, 1920, 3) fp32; x = img[3:-3] -> (1074, 1920, 3)
//   vertical median, window 5, symmetric padding along axis 0.
#define N_ROWS 1074          // output rows
#define ROW_V4 1440          // float4 per row (1920*3/4)
#define RPB    16            // output rows per thread (rolling window)

// Native clang vector type: __builtin_nontemporal_store accepts this
// (HIP's float4 is a struct and is rejected).
typedef float vfloat4 __attribute__((ext_vector_type(4)));

__device__ __forceinline__ void cswap(float& a, float& b) {
    float lo = fminf(a, b);
    b = fmaxf(a, b);
    a = lo;
}

// Devillard opt_med5: 7 compare-exchanges, result in p2.
__device__ __forceinline__ float med5(float p0, float p1, float p2, float p3, float p4) {
    cswap(p0, p1); cswap(p3, p4); cswap(p0, p3);
    cswap(p1, p4); cswap(p1, p2); cswap(p2, p3);
    cswap(p1, p2);
    return p2;
}

__device__ __forceinline__ vfloat4 med5v(const vfloat4& a, const vfloat4& b,
                                         const vfloat4& c, const vfloat4& d,
                                         const vfloat4& e) {
    vfloat4 r;
    r.x = med5(a.x, b.x, c.x, d.x, e.x);
    r.y = med5(a.y, b.y, c.y, d.y, e.y);
    r.z = med5(a.z, b.z, c.z, d.z, e.z);
    r.w = med5(a.w, b.w, c.w, d.w, e.w);
    return r;
}

__global__ __launch_bounds__(256)
void VerticalMedian_54262616818099_kernel(const float* __restrict__ img,
                                          float* __restrict__ out) {
    const int c4 = blockIdx.x * 256 + threadIdx.x;   // vfloat4 column index
    if (c4 >= ROW_V4) return;
    const int i0 = blockIdx.y * RPB;                 // first output row of strip

    const vfloat4* __restrict__ in4 = (const vfloat4*)img + c4;
    vfloat4* __restrict__ o4 = (vfloat4*)out + c4;

    // Load one (reflected) window row; +3 crops img[3:-3].
    auto ld = [&](int j) -> vfloat4 {
        j = (j < 0) ? (-1 - j) : j;                    // symmetric reflect top
        j = (j >= N_ROWS) ? (2 * N_ROWS - 1 - j) : j;  // symmetric reflect bottom
        return in4[(size_t)(j + 3) * ROW_V4];
    };

    // Prime 4 rows of the 5-row rolling window.
    vfloat4 w0 = ld(i0 - 2), w1 = ld(i0 - 1), w2 = ld(i0), w3 = ld(i0 + 1);

#pragma unroll
    for (int r = 0; r < RPB; ++r) {
        const int i = i0 + r;
        if (i >= N_ROWS) break;                        // partial last strip (rows 1072-73)
        vfloat4 w4 = ld(i + 2);                        // 1 new load per output row
        vfloat4 m = med5v(w0, w1, w2, w3, w4);
        // Output is never re-read: non-temporal store keeps L2 for input halo reuse.
        __builtin_nontemporal_store(m, &o4[(size_t)i * ROW_V4]);
        w0 = w1; w1 = w2; w2 = w3; w3 = w4;
    }
}

extern "C" void kernel_launch(void* const* d_in, const int* in_sizes, int n_in,
                              void* d_out, int out_size, void* d_ws, size_t ws_size,
                              hipStream_t stream) {
    const float* img = (const float*)d_in[0];
    // d_in[1] = mask (unused by reference output), d_in[2] = vertical_size (fixed 5)
    float* out = (float*)d_out;

    dim3 block(256, 1, 1);
    dim3 grid((ROW_V4 + 255) / 256,                    // 6 column chunks
              (N_ROWS + RPB - 1) / RPB, 1);            // 68 row strips
    VerticalMedian_54262616818099_kernel<<<grid, block, 0, stream>>>(img, out);
}

// Round 5
// 83.147 us; speedup vs baseline: 1.0515x; 1.0515x over previous
//
#include <hip/hip_runtime.h>

// Problem geometry (fixed by setup_inputs):
//   img: (1080, 1920, 3) fp32; x = img[3:-3] -> (1074, 1920, 3)
//   vertical median, window 5, symmetric padding along axis 0.
// Best measured config (R2): RPB=8 rolling window, plain stores.
//   RPB=16 + nontemporal stores regressed (R4: 87.4 vs 83.6 µs) — fewer
//   blocks (408 vs 810 → 1.6 vs 3.2 blocks/CU) hurt latency hiding more
//   than the halo-read saving helped.
#define N_ROWS 1074          // output rows
#define ROW_V4 1440          // float4 per row (1920*3/4)
#define RPB    8             // output rows per thread (rolling window)

__device__ __forceinline__ void cswap(float& a, float& b) {
    float lo = fminf(a, b);
    b = fmaxf(a, b);
    a = lo;
}

// Devillard opt_med5: 7 compare-exchanges, result in p2.
__device__ __forceinline__ float med5(float p0, float p1, float p2, float p3, float p4) {
    cswap(p0, p1); cswap(p3, p4); cswap(p0, p3);
    cswap(p1, p4); cswap(p1, p2); cswap(p2, p3);
    cswap(p1, p2);
    return p2;
}

__device__ __forceinline__ float4 med5v(const float4& a, const float4& b,
                                        const float4& c, const float4& d,
                                        const float4& e) {
    float4 r;
    r.x = med5(a.x, b.x, c.x, d.x, e.x);
    r.y = med5(a.y, b.y, c.y, d.y, e.y);
    r.z = med5(a.z, b.z, c.z, d.z, e.z);
    r.w = med5(a.w, b.w, c.w, d.w, e.w);
    return r;
}

__global__ __launch_bounds__(256)
void VerticalMedian_54262616818099_kernel(const float* __restrict__ img,
                                          float* __restrict__ out) {
    const int c4 = blockIdx.x * 256 + threadIdx.x;   // float4 column index
    if (c4 >= ROW_V4) return;
    const int i0 = blockIdx.y * RPB;                 // first output row of strip

    const float4* __restrict__ in4 = (const float4*)img + c4;
    float4* __restrict__ o4 = (float4*)out + c4;

    // Load one (reflected) window row; +3 crops img[3:-3].
    auto ld = [&](int j) -> float4 {
        j = (j < 0) ? (-1 - j) : j;                    // symmetric reflect top
        j = (j >= N_ROWS) ? (2 * N_ROWS - 1 - j) : j;  // symmetric reflect bottom
        return in4[(size_t)(j + 3) * ROW_V4];
    };

    // Prime 4 rows of the 5-row rolling window.
    float4 w0 = ld(i0 - 2), w1 = ld(i0 - 1), w2 = ld(i0), w3 = ld(i0 + 1);

#pragma unroll
    for (int r = 0; r < RPB; ++r) {
        const int i = i0 + r;
        if (i >= N_ROWS) break;                        // partial last strip
        float4 w4 = ld(i + 2);                         // 1 new load per output row
        o4[(size_t)i * ROW_V4] = med5v(w0, w1, w2, w3, w4);
        w0 = w1; w1 = w2; w2 = w3; w3 = w4;
    }
}

extern "C" void kernel_launch(void* const* d_in, const int* in_sizes, int n_in,
                              void* d_out, int out_size, void* d_ws, size_t ws_size,
                              hipStream_t stream) {
    const float* img = (const float*)d_in[0];
    // d_in[1] = mask (unused by reference output), d_in[2] = vertical_size (fixed 5)
    float* out = (float*)d_out;

    dim3 block(256, 1, 1);
    dim3 grid((ROW_V4 + 255) / 256,                    // 6 column chunks
              (N_ROWS + RPB - 1) / RPB, 1);            // 135 row strips
    VerticalMedian_54262616818099_kernel<<<grid, block, 0, stream>>>(img, out);
}